// Round 9
// baseline (306.819 us; speedup 1.0000x reference)
//
#include <hip/hip_runtime.h>

// CRF forward: B=512 chains, T=1024, L=48.
// One launch of 1024 blocks:
//   blocks 0..511   : serial alpha-scan, one wave per chain (reads y_pred only)
//   blocks 512..1023: point+trans scores, PARALLEL over t (lane j <-> t0+j)
// Combined into out[b] via two atomicAdds after hipMemsetAsync(out, 0).
//
// Scan step (R8): broadcast via ds_bpermute (VGPR->VGPR lane crossbar, DS
// pipe, no LDS write/read round trip, no SGPR hazards). 48 independent
// bpermutes pipeline at ~30-40cy and co-issue with the 48 VGPR fmacs
// (R7's v_readlane->SGPR->fmac chain cost ~4cy/pair in hazards/issue).
// Index VGPRs (4*l) pinned loop-invariant via opaque asm.
// Normalizer: damped lag-2 (c_t = 0.5*log2(e_{t-2}[0]), poles |z|=0.707,
// stable; validated R5-R7 absmax=0). Exactness independent of c.

constexpr int Bb = 512;
constexpr int Tt = 1024;
constexpr int Ll = 48;
constexpr int PF = 4;   // scan prefetch depth (steps)

#define LOG2E_F 1.44269504088896340736f
#define LN2_F   0.69314718055994530942f

__device__ __forceinline__ float rl_f(float v, int l) {
    return __uint_as_float(__builtin_amdgcn_readlane(__float_as_uint(v), (unsigned)l));
}
__device__ __forceinline__ float fexp2(float x) {
    return __builtin_amdgcn_exp2f(x);
}
__device__ __forceinline__ float flog2(float x) {
    return __builtin_amdgcn_logf(x);   // v_log_f32 = log2
}

__global__ __launch_bounds__(64)
__attribute__((amdgpu_waves_per_eu(1, 1)))
void crf_fwd_kernel(const float* __restrict__ y_true,
                    const float* __restrict__ y_pred,
                    const float* __restrict__ trans,
                    float* __restrict__ out)
{
    const int lane = threadIdx.x;

    __shared__ float str[Ll * Ll];

    if (blockIdx.x >= Bb) {
        // -------- score block: chain b, parallel over t (lane j = t0+j) ----
        const int b = blockIdx.x - Bb;
        for (int i = lane; i < Ll * Ll; i += 64) str[i] = trans[i];
        __syncthreads();

        const float* __restrict__ yprow = y_pred + (size_t)b * Tt * Ll;
        const float* __restrict__ ytrow = y_true + (size_t)b * Tt * Ll;

        float ps = 0.f, ts = 0.f;
        int labLast = 0;                         // lab at t0-1 (unused for t=0)

        for (int t0 = 0; t0 < Tt; t0 += 64) {
            const int t = t0 + lane;
            // label of row t: 12 independent float4 loads + predicated selects
            const float4* row = (const float4*)(ytrow + (size_t)t * Ll);
            int lab = 0;
            #pragma unroll
            for (int k = 0; k < 12; ++k) {
                float4 v = row[k];
                if (v.x > 0.5f) lab = 4 * k + 0;
                if (v.y > 0.5f) lab = 4 * k + 1;
                if (v.z > 0.5f) lab = 4 * k + 2;
                if (v.w > 0.5f) lab = 4 * k + 3;
            }
            ps += yprow[(size_t)t * Ll + lab];            // point term
            int labPrev = __shfl_up(lab, 1);
            if (lane == 0) labPrev = labLast;             // chunk boundary
            if (t > 0) ts += str[labPrev * Ll + lab];     // trans term
            labLast = __builtin_amdgcn_readlane(lab, 63);
        }

        float acc = ps + ts;
        #pragma unroll
        for (int off = 32; off >= 1; off >>= 1) acc += __shfl_xor(acc, off);
        if (lane == 0) atomicAdd(&out[b], -acc);
        return;
    }

    // ---------------- scan block: chain b = blockIdx.x --------------------
    const int b  = blockIdx.x;
    const int ml = lane < Ll ? lane : (Ll - 1);
    const bool act = lane < Ll;
    for (int i = lane; i < Ll * Ll; i += 64) str[i] = trans[i];
    __syncthreads();

    // Et[l] = exp(trans[l][ml]) as 48 named scalars (static accesses only)
#define MK_E(l) float E##l = fexp2(str[(l) * Ll + ml] * LOG2E_F);
    MK_E(0)  MK_E(1)  MK_E(2)  MK_E(3)  MK_E(4)  MK_E(5)  MK_E(6)  MK_E(7)
    MK_E(8)  MK_E(9)  MK_E(10) MK_E(11) MK_E(12) MK_E(13) MK_E(14) MK_E(15)
    MK_E(16) MK_E(17) MK_E(18) MK_E(19) MK_E(20) MK_E(21) MK_E(22) MK_E(23)
    MK_E(24) MK_E(25) MK_E(26) MK_E(27) MK_E(28) MK_E(29) MK_E(30) MK_E(31)
    MK_E(32) MK_E(33) MK_E(34) MK_E(35) MK_E(36) MK_E(37) MK_E(38) MK_E(39)
    MK_E(40) MK_E(41) MK_E(42) MK_E(43) MK_E(44) MK_E(45) MK_E(46) MK_E(47)
#undef MK_E

    // bpermute byte-index VGPRs (4*l), pinned loop-invariant & opaque so the
    // compiler keeps them register-resident (can't rematerialize per step)
#define MK_I(l) int I##l = 4 * (l); asm("" : "+v"(I##l));
    MK_I(0)  MK_I(1)  MK_I(2)  MK_I(3)  MK_I(4)  MK_I(5)  MK_I(6)  MK_I(7)
    MK_I(8)  MK_I(9)  MK_I(10) MK_I(11) MK_I(12) MK_I(13) MK_I(14) MK_I(15)
    MK_I(16) MK_I(17) MK_I(18) MK_I(19) MK_I(20) MK_I(21) MK_I(22) MK_I(23)
    MK_I(24) MK_I(25) MK_I(26) MK_I(27) MK_I(28) MK_I(29) MK_I(30) MK_I(31)
    MK_I(32) MK_I(33) MK_I(34) MK_I(35) MK_I(36) MK_I(37) MK_I(38) MK_I(39)
    MK_I(40) MK_I(41) MK_I(42) MK_I(43) MK_I(44) MK_I(45) MK_I(46) MK_I(47)
#undef MK_I

    const float* __restrict__ yprow = y_pred + (size_t)b * Tt * Ll;

    float raw0 = yprow[ml];
    float e = fexp2(raw0 * LOG2E_F);                  // e_0[m], S = 0
    float S = 0.f;
    float cUse = 0.5f * rl_f(raw0, 0) * LOG2E_F;      // 0.5*log2(e_0[0])

    // one broadcast-fmac: acc += bpermute(e, lane l) * Et[l][m]
#define BPF(l, acc)                                                      \
    { int bb = __builtin_amdgcn_ds_bpermute(I##l, ei);                   \
      acc = fmaf(__uint_as_float((unsigned)bb), E##l, acc); }

#define STEP(raw)                                                        \
    do {                                                                 \
        int ei = __float_as_uint(e);                                     \
        float cNew = 0.5f * flog2(rl_f(e, 0));                           \
        cNew = fminf(50.f, fmaxf(-50.f, cNew));                          \
        float w = fexp2(fmaf((raw), LOG2E_F, -cUse));                    \
        S += cUse;                                                       \
        cUse = cNew;                                                     \
        float a0 = 0.f, a1 = 0.f, a2 = 0.f, a3 = 0.f;                    \
        float a4 = 0.f, a5 = 0.f, a6 = 0.f, a7 = 0.f;                    \
        BPF(0,  a0) BPF(1,  a1) BPF(2,  a2) BPF(3,  a3)                  \
        BPF(4,  a4) BPF(5,  a5) BPF(6,  a6) BPF(7,  a7)                  \
        BPF(8,  a0) BPF(9,  a1) BPF(10, a2) BPF(11, a3)                  \
        BPF(12, a4) BPF(13, a5) BPF(14, a6) BPF(15, a7)                  \
        BPF(16, a0) BPF(17, a1) BPF(18, a2) BPF(19, a3)                  \
        BPF(20, a4) BPF(21, a5) BPF(22, a6) BPF(23, a7)                  \
        BPF(24, a0) BPF(25, a1) BPF(26, a2) BPF(27, a3)                  \
        BPF(28, a4) BPF(29, a5) BPF(30, a6) BPF(31, a7)                  \
        BPF(32, a0) BPF(33, a1) BPF(34, a2) BPF(35, a3)                  \
        BPF(36, a4) BPF(37, a5) BPF(38, a6) BPF(39, a7)                  \
        BPF(40, a0) BPF(41, a1) BPF(42, a2) BPF(43, a3)                  \
        BPF(44, a4) BPF(45, a5) BPF(46, a6) BPF(47, a7)                  \
        e = (((a0 + a1) + (a2 + a3)) + ((a4 + a5) + (a6 + a7))) * w;     \
    } while (0)

    float pfP[PF];
    #pragma unroll
    for (int j = 0; j < PF; ++j) pfP[j] = yprow[(1 + j) * Ll + ml];

    for (int t0 = 1; t0 <= Tt - PF - 3; t0 += PF) {
        #pragma unroll
        for (int j = 0; j < PF; ++j) {
            float raw = pfP[j];
            int tn = t0 + j + PF;
            tn = tn < Tt ? tn : (Tt - 1);       // clamp (harmless reload)
            pfP[j] = yprow[tn * Ll + ml];
            STEP(raw);
        }
    }
    STEP(pfP[0]);
    STEP(pfP[1]);
    STEP(pfP[2]);
#undef STEP
#undef BPF

    float es = act ? e : 0.f;
    #pragma unroll
    for (int off = 32; off >= 1; off >>= 1) es += __shfl_xor(es, off);

    if (lane == 0)
        atomicAdd(&out[b], LN2_F * (S + flog2(es)));
}

extern "C" void kernel_launch(void* const* d_in, const int* in_sizes, int n_in,
                              void* d_out, int out_size, void* d_ws, size_t ws_size,
                              hipStream_t stream) {
    const float* y_true = (const float*)d_in[0];
    const float* y_pred = (const float*)d_in[1];
    const float* trans  = (const float*)d_in[2];
    float* out = (float*)d_out;

    hipMemsetAsync(d_out, 0, (size_t)out_size * sizeof(float), stream);
    crf_fwd_kernel<<<2 * Bb, 64, 0, stream>>>(y_true, y_pred, trans, out);
}

// Round 10
// 235.381 us; speedup vs baseline: 1.3035x; 1.3035x over previous
//
#include <hip/hip_runtime.h>

// CRF forward: B=512 chains, T=1024, L=48.
// blocks 0..511: serial alpha-scan (1 wave/chain). blocks 512..1023: scores,
// parallel over t. Combined via atomicAdd after memset. (validated R6-R8)
//
// Scan step (R9): DPP-fused matvec. out[m] = sum_{c,i} ecopy_c[ror_i(m)]*C_{c,i}[m].
// 48 x "v_fmac_f32 acc, ecopy, coef row_ror:i" -- rotation is an input
// modifier, zero extra broadcast instructions. Only 2 ds_bpermute/step build
// the group-rotated copies (latency hidden under the c=0 fmac block).
// DPP direction is PROBED at setup (v_mov row_ror:i on lane id) and folded
// into the coefficients -> correct for either rotation convention.
// Normalizer: damped lag-2 (validated R5-R8, absmax=0). Exact regardless of c.

constexpr int Bb = 512;
constexpr int Tt = 1024;
constexpr int Ll = 48;
constexpr int PF = 4;

#define LOG2E_F 1.44269504088896340736f
#define LN2_F   0.69314718055994530942f

__device__ __forceinline__ float rl_f(float v, int l) {
    return __uint_as_float(__builtin_amdgcn_readlane(__float_as_uint(v), (unsigned)l));
}
__device__ __forceinline__ float fexp2(float x) { return __builtin_amdgcn_exp2f(x); }
__device__ __forceinline__ float flog2(float x) { return __builtin_amdgcn_logf(x); }

__global__ __launch_bounds__(64)
__attribute__((amdgpu_waves_per_eu(1, 1)))
void crf_fwd_kernel(const float* __restrict__ y_true,
                    const float* __restrict__ y_pred,
                    const float* __restrict__ trans,
                    float* __restrict__ out)
{
    const int lane = threadIdx.x;

    __shared__ float str[Ll * Ll];

    if (blockIdx.x >= Bb) {
        // -------- score block: chain b, parallel over t (lane j = t0+j) ----
        const int b = blockIdx.x - Bb;
        for (int i = lane; i < Ll * Ll; i += 64) str[i] = trans[i];
        __syncthreads();

        const float* __restrict__ yprow = y_pred + (size_t)b * Tt * Ll;
        const float* __restrict__ ytrow = y_true + (size_t)b * Tt * Ll;

        float ps = 0.f, ts = 0.f;
        int labLast = 0;

        for (int t0 = 0; t0 < Tt; t0 += 64) {
            const int t = t0 + lane;
            const float4* row = (const float4*)(ytrow + (size_t)t * Ll);
            int lab = 0;
            #pragma unroll
            for (int k = 0; k < 12; ++k) {
                float4 v = row[k];
                if (v.x > 0.5f) lab = 4 * k + 0;
                if (v.y > 0.5f) lab = 4 * k + 1;
                if (v.z > 0.5f) lab = 4 * k + 2;
                if (v.w > 0.5f) lab = 4 * k + 3;
            }
            ps += yprow[(size_t)t * Ll + lab];
            int labPrev = __shfl_up(lab, 1);
            if (lane == 0) labPrev = labLast;
            if (t > 0) ts += str[labPrev * Ll + lab];
            labLast = __builtin_amdgcn_readlane(lab, 63);
        }

        float acc = ps + ts;
        #pragma unroll
        for (int off = 32; off >= 1; off >>= 1) acc += __shfl_xor(acc, off);
        if (lane == 0) atomicAdd(&out[b], -acc);
        return;
    }

    // ---------------- scan block: chain b = blockIdx.x --------------------
    const int b  = blockIdx.x;
    const int ml = lane < Ll ? lane : (Ll - 1);
    const bool act = lane < Ll;
    const int g = lane >> 4;          // DPP row group (3 = garbage lanes)
    const int r = lane & 15;
    for (int i = lane; i < Ll * Ll; i += 64) str[i] = trans[i];
    __syncthreads();

    // --- probe the row_ror source-lane mapping (direction-agnostic) -------
#define PROBE(i) int P##i; \
    asm volatile("s_nop 1\n\tv_mov_b32 %0, %1 row_ror:" #i : "=v"(P##i) : "v"(lane));
    PROBE(1)  PROBE(2)  PROBE(3)  PROBE(4)  PROBE(5)  PROBE(6)  PROBE(7)
    PROBE(8)  PROBE(9)  PROBE(10) PROBE(11) PROBE(12) PROBE(13) PROBE(14) PROBE(15)
#undef PROBE

    // --- coefficients: C_{c,i}[m] = exp(trans[16*((g+c)%3) + srcr_i][ml]) --
#define MK_C(c, i, SR) float C_##c##_##i = \
    fexp2(str[(16 * ((g + (c)) % 3) + (SR)) * Ll + ml] * LOG2E_F);
#define MK_CI(i) MK_C(0, i, (P##i & 15)) MK_C(1, i, (P##i & 15)) MK_C(2, i, (P##i & 15))
    MK_C(0, 0, r) MK_C(1, 0, r) MK_C(2, 0, r)
    MK_CI(1)  MK_CI(2)  MK_CI(3)  MK_CI(4)  MK_CI(5)
    MK_CI(6)  MK_CI(7)  MK_CI(8)  MK_CI(9)  MK_CI(10)
    MK_CI(11) MK_CI(12) MK_CI(13) MK_CI(14) MK_CI(15)
#undef MK_CI
#undef MK_C

    // bpermute byte-indices for the two group-rotated copies (loop-invariant)
    int idx1 = 4 * (16 * ((g + 1) % 3) + r);
    int idx2 = 4 * (16 * ((g + 2) % 3) + r);

    const float* __restrict__ yprow = y_pred + (size_t)b * Tt * Ll;

    float raw0 = yprow[ml];
    float e = fexp2(raw0 * LOG2E_F);                  // e_0[m], S = 0
    float S = 0.f;
    float cUse = 0.5f * rl_f(raw0, 0) * LOG2E_F;

    // fused DPP fmac: acc += ecopy[ror_i(lane)] * C_{c,i}
#define FD(c, i, acc) asm volatile("v_fmac_f32 %0, %1, %2 row_ror:" #i \
        : "+v"(acc) : "v"(ec##c), "v"(C_##c##_##i));
#define F0(c, acc) asm volatile("v_fmac_f32 %0, %1, %2" \
        : "+v"(acc) : "v"(ec##c), "v"(C_##c##_0));

#define STEP(raw)                                                        \
    do {                                                                 \
        int ei = __float_as_uint(e);                                     \
        float ec0 = e;                                                   \
        float ec1 = __uint_as_float((unsigned)__builtin_amdgcn_ds_bpermute(idx1, ei)); \
        float ec2 = __uint_as_float((unsigned)__builtin_amdgcn_ds_bpermute(idx2, ei)); \
        float cNew = 0.5f * flog2(rl_f(e, 0));                           \
        cNew = fminf(50.f, fmaxf(-50.f, cNew));                          \
        float w = fexp2(fmaf((raw), LOG2E_F, -cUse));                    \
        S += cUse;                                                       \
        cUse = cNew;                                                     \
        float a0 = 0.f, a1 = 0.f, a2 = 0.f, a3 = 0.f;                    \
        float a4 = 0.f, a5 = 0.f, a6 = 0.f, a7 = 0.f;                    \
        asm volatile("s_nop 1");                                         \
        F0(0, a0)      FD(0, 1,  a1) FD(0, 2,  a2) FD(0, 3,  a3)         \
        FD(0, 4,  a4)  FD(0, 5,  a5) FD(0, 6,  a6) FD(0, 7,  a7)         \
        FD(0, 8,  a0)  FD(0, 9,  a1) FD(0, 10, a2) FD(0, 11, a3)         \
        FD(0, 12, a4)  FD(0, 13, a5) FD(0, 14, a6) FD(0, 15, a7)         \
        F0(1, a0)      FD(1, 1,  a1) FD(1, 2,  a2) FD(1, 3,  a3)         \
        FD(1, 4,  a4)  FD(1, 5,  a5) FD(1, 6,  a6) FD(1, 7,  a7)         \
        FD(1, 8,  a0)  FD(1, 9,  a1) FD(1, 10, a2) FD(1, 11, a3)         \
        FD(1, 12, a4)  FD(1, 13, a5) FD(1, 14, a6) FD(1, 15, a7)         \
        F0(2, a0)      FD(2, 1,  a1) FD(2, 2,  a2) FD(2, 3,  a3)         \
        FD(2, 4,  a4)  FD(2, 5,  a5) FD(2, 6,  a6) FD(2, 7,  a7)         \
        FD(2, 8,  a0)  FD(2, 9,  a1) FD(2, 10, a2) FD(2, 11, a3)         \
        FD(2, 12, a4)  FD(2, 13, a5) FD(2, 14, a6) FD(2, 15, a7)         \
        e = (((a0 + a1) + (a2 + a3)) + ((a4 + a5) + (a6 + a7))) * w;     \
    } while (0)

    float pfP[PF];
    #pragma unroll
    for (int j = 0; j < PF; ++j) pfP[j] = yprow[(1 + j) * Ll + ml];

    for (int t0 = 1; t0 <= Tt - PF - 3; t0 += PF) {
        #pragma unroll
        for (int j = 0; j < PF; ++j) {
            float raw = pfP[j];
            int tn = t0 + j + PF;
            tn = tn < Tt ? tn : (Tt - 1);
            pfP[j] = yprow[tn * Ll + ml];
            STEP(raw);
        }
    }
    STEP(pfP[0]);
    STEP(pfP[1]);
    STEP(pfP[2]);
#undef STEP
#undef FD
#undef F0

    float es = act ? e : 0.f;
    #pragma unroll
    for (int off = 32; off >= 1; off >>= 1) es += __shfl_xor(es, off);

    if (lane == 0)
        atomicAdd(&out[b], LN2_F * (S + flog2(es)));
}

extern "C" void kernel_launch(void* const* d_in, const int* in_sizes, int n_in,
                              void* d_out, int out_size, void* d_ws, size_t ws_size,
                              hipStream_t stream) {
    const float* y_true = (const float*)d_in[0];
    const float* y_pred = (const float*)d_in[1];
    const float* trans  = (const float*)d_in[2];
    float* out = (float*)d_out;

    hipMemsetAsync(d_out, 0, (size_t)out_size * sizeof(float), stream);
    crf_fwd_kernel<<<2 * Bb, 64, 0, stream>>>(y_true, y_pred, trans, out);
}